// Round 3
// baseline (1260.314 us; speedup 1.0000x reference)
//
#include <hip/hip_runtime.h>
#include <stdint.h>

#define GLOBAL_AS __attribute__((address_space(1)))
#define LDS_AS    __attribute__((address_space(3)))

typedef __attribute__((ext_vector_type(8))) short bf16x8;   // 8 bf16 = 4 VGPRs
typedef __attribute__((ext_vector_type(4))) float f32x4;

#define B_DIM 2048
#define D_DIM 4096
#define Q_DIM 1024
#define EPSF  1e-8f

__device__ __forceinline__ unsigned short f2bf(float f) {
  union { float f; unsigned int u; } v; v.f = f;
  unsigned int u = v.u;
  u += 0x7FFFu + ((u >> 16) & 1u);   // round-to-nearest-even
  return (unsigned short)(u >> 16);
}

// ---------------- K0: f32 -> bf16 conversion (x, W_phi, W_dde) ----------------
#define NX4    2097152u   // 2048*4096/4
#define NWPHI4 4194304u   // 4096*4096/4
#define NWDDE4 1048576u   // 1024*4096/4

__global__ __launch_bounds__(256) void k_convert(
    const float* __restrict__ x, const float* __restrict__ wphi,
    const float* __restrict__ wdde,
    unsigned short* __restrict__ xb, unsigned short* __restrict__ wphib,
    unsigned short* __restrict__ wddeb, float* __restrict__ drift) {
  unsigned int idx = blockIdx.x * 256u + threadIdx.x;
  if (idx == 0) *drift = 0.0f;
  const float4* s; ushort4* d; unsigned int local;
  if (idx < NX4)              { s = (const float4*)x;    d = (ushort4*)xb;    local = idx; }
  else if (idx < NX4 + NWPHI4){ s = (const float4*)wphi; d = (ushort4*)wphib; local = idx - NX4; }
  else                        { s = (const float4*)wdde; d = (ushort4*)wddeb; local = idx - (NX4 + NWPHI4); }
  float4 v = s[local];
  d[local] = make_ushort4(f2bf(v.x), f2bf(v.y), f2bf(v.z), f2bf(v.w));
}

// ---------------- K1: GEMM1 (v = x * W_phi^T) + quaternion epilogue ----------------
// A = x bf16 [2048,4096], B = W_phi bf16 [4096,4096] (both K-contiguous).
// 128x128 tile, BK=32, 256 threads = 4 waves in 2x2, each wave 64x64 (4x4 MFMA tiles).
// Epilogue: per-wave LDS transpose (no shfl) -> each lane handles whole quaternions.
__global__ __launch_bounds__(256) void k_gemm1(
    const unsigned short* __restrict__ A, const unsigned short* __restrict__ Bm,
    const float* __restrict__ bphi, const float* __restrict__ state,
    float* __restrict__ nsf /* d_out as [2048,4096] f32 next_state */,
    unsigned short* __restrict__ nsb /* ws: next_state bf16 */,
    float* __restrict__ drift) {
  __shared__ __align__(16) unsigned short sAB[2 * 128 * 32];  // sA=[0,4096), sB=[4096,8192)
  const int t = threadIdx.x;
  const int lane = t & 63;
  const int w = t >> 6;
  const int bn = blockIdx.x;   // 0..31  (cols = W_phi rows)
  const int bm = blockIdx.y;   // 0..15  (x rows)
  const int rowA0 = bm * 128;
  const int rowB0 = bn * 128;

  // staging: chunk c covers 16B; row = c>>2, k-offset = (c&3)*8 elements
  const int c0 = t, c1 = t + 256;
  const unsigned short* gA0 = A  + (size_t)(rowA0 + (c0 >> 2)) * D_DIM + (c0 & 3) * 8;
  const unsigned short* gA1 = A  + (size_t)(rowA0 + (c1 >> 2)) * D_DIM + (c1 & 3) * 8;
  const unsigned short* gB0 = Bm + (size_t)(rowB0 + (c0 >> 2)) * D_DIM + (c0 & 3) * 8;
  const unsigned short* gB1 = Bm + (size_t)(rowB0 + (c1 >> 2)) * D_DIM + (c1 & 3) * 8;
  unsigned short* lA0 = &sAB[c0 * 8];
  unsigned short* lA1 = &sAB[c1 * 8];
  unsigned short* lB0 = &sAB[4096 + c0 * 8];
  unsigned short* lB1 = &sAB[4096 + c1 * 8];

  f32x4 acc[4][4] = {};
  const int lm = lane & 15;
  const int lq = lane >> 4;
  const int mbase = (w >> 1) * 64;
  const int nbase = (w & 1) * 64;

  for (int k0 = 0; k0 < D_DIM; k0 += 32) {
    __builtin_amdgcn_global_load_lds((const GLOBAL_AS unsigned int*)(gA0 + k0), (LDS_AS unsigned int*)lA0, 16, 0, 0);
    __builtin_amdgcn_global_load_lds((const GLOBAL_AS unsigned int*)(gA1 + k0), (LDS_AS unsigned int*)lA1, 16, 0, 0);
    __builtin_amdgcn_global_load_lds((const GLOBAL_AS unsigned int*)(gB0 + k0), (LDS_AS unsigned int*)lB0, 16, 0, 0);
    __builtin_amdgcn_global_load_lds((const GLOBAL_AS unsigned int*)(gB1 + k0), (LDS_AS unsigned int*)lB1, 16, 0, 0);
    __syncthreads();
    bf16x8 af[4], bfr[4];
#pragma unroll
    for (int i = 0; i < 4; ++i)
      af[i] = *(const bf16x8*)&sAB[(mbase + i * 16 + lm) * 32 + lq * 8];
#pragma unroll
    for (int j = 0; j < 4; ++j)
      bfr[j] = *(const bf16x8*)&sAB[4096 + (nbase + j * 16 + lm) * 32 + lq * 8];
#pragma unroll
    for (int i = 0; i < 4; ++i)
#pragma unroll
      for (int j = 0; j < 4; ++j)
        acc[i][j] = __builtin_amdgcn_mfma_f32_16x16x32_bf16(af[i], bfr[j], acc[i][j], 0, 0, 0);
    __syncthreads();
  }

  // ---- epilogue: per-wave 16x64 f32 scratch in the (now free) staging LDS ----
  // C/D layout: col = lane&15, row = (lane>>4)*4 + reg  [m89-verified]
  float* cscr = ((float*)sAB) + w * 1024;       // 4 KB per wave, 16 KB total
  float driftLocal = 0.0f;
  const int colBase = rowB0 + nbase;            // wave's global col 0 (multiple of 64)
  const int qBase = colBase >> 2;               // global quaternion base
#pragma unroll 1
  for (int i = 0; i < 4; ++i) {
    __syncthreads();                            // previous iter's reads done (all waves)
#pragma unroll
    for (int j = 0; j < 4; ++j)
#pragma unroll
      for (int r = 0; r < 4; ++r)
        cscr[(lq * 4 + r) * 64 + j * 16 + lm] = acc[i][j][r];
    __syncthreads();                            // writes visible
#pragma unroll
    for (int s = 0; s < 4; ++s) {
      const int qlin = s * 64 + lane;           // 0..255 over 16 rows x 16 quats
      const int lrow = qlin >> 4;               // 0..15
      const int qc = qlin & 15;                 // 0..15
      float4 vq = *(const float4*)&cscr[lrow * 64 + qc * 4];
      float4 bq = ((const float4*)bphi)[qBase + qc];
      float vx = vq.y + bq.y, vy = vq.z + bq.z, vz = vq.w + bq.w;  // v[...,1:]
      // exp_map (reference: theta includes +EPS; axis = v/theta)
      float th = sqrtf(vx * vx + vy * vy + vz * vz) + EPSF;
      float st = sinf(th), ct = cosf(th);
      float sc = st / th;
      float rw = ct, rx = vx * sc, ry = vy * sc, rz = vz * sc;
      const int grow = rowA0 + mbase + i * 16 + lrow;
      const size_t qgi = (size_t)grow * Q_DIM + (qBase + qc);
      float4 sq = ((const float4*)state)[qgi];
      float aw = sq.x, ax = sq.y, ay = sq.z, az = sq.w;
      // qmul(state, rotation)
      float nw = aw * rw - ax * rx - ay * ry - az * rz;
      float nx = aw * rx + rw * ax + (ay * rz - az * ry);
      float ny = aw * ry + rw * ay + (az * rx - ax * rz);
      float nz = aw * rz + rw * az + (ax * ry - ay * rx);
      // qnormalize
      float nrm = sqrtf(nw * nw + nx * nx + ny * ny + nz * nz);
      float invn = 1.0f / (nrm + EPSF);
      nw *= invn; nx *= invn; ny *= invn; nz *= invn;
      float n2 = sqrtf(nw * nw + nx * nx + ny * ny + nz * nz);
      driftLocal += fabsf(n2 - 1.0f);
      float4 o; o.x = nw; o.y = nx; o.z = ny; o.w = nz;
      ((float4*)nsf)[qgi] = o;                  // f32 next_state (blend source)
      ((ushort4*)nsb)[qgi] = make_ushort4(f2bf(nw), f2bf(nx), f2bf(ny), f2bf(nz));
    }
  }
#pragma unroll
  for (int off = 32; off > 0; off >>= 1) driftLocal += __shfl_down(driftLocal, off);
  if (lane == 0) atomicAdd(drift, driftLocal);
}

// ---------------- K2: GEMM2 (logits = ns * W_dde^T) + gate/blend epilogue ----------------
// 128x64 tile -> 16x16 = 256 blocks. 4 waves in 2x2, each wave 64x32 (4x2 MFMA tiles).
__global__ __launch_bounds__(256) void k_gemm2(
    const unsigned short* __restrict__ A /* ns bf16 [2048,4096] */,
    const unsigned short* __restrict__ Bm /* W_dde bf16 [1024,4096] */,
    const float* __restrict__ bdde, const float* __restrict__ state,
    float* __restrict__ out /* d_out f32: holds ns, overwritten in place */) {
  __shared__ unsigned short sA[128 * 32];  // 8 KB
  __shared__ unsigned short sB[64 * 32];   // 4 KB
  const int t = threadIdx.x;
  const int lane = t & 63;
  const int w = t >> 6;
  const int bn = blockIdx.x;  // 0..15 (q tiles)
  const int bm = blockIdx.y;  // 0..15 (rows)
  const int rowA0 = bm * 128;
  const int rowB0 = bn * 64;
  const int c0 = t, c1 = t + 256;
  const unsigned short* gA0 = A  + (size_t)(rowA0 + (c0 >> 2)) * D_DIM + (c0 & 3) * 8;
  const unsigned short* gA1 = A  + (size_t)(rowA0 + (c1 >> 2)) * D_DIM + (c1 & 3) * 8;
  const unsigned short* gB0 = Bm + (size_t)(rowB0 + (c0 >> 2)) * D_DIM + (c0 & 3) * 8;
  unsigned short* lA0 = &sA[c0 * 8];
  unsigned short* lA1 = &sA[c1 * 8];
  unsigned short* lB0 = &sB[c0 * 8];

  f32x4 acc[4][2] = {};
  const int lm = lane & 15, lq = lane >> 4;
  const int mbase = (w >> 1) * 64, nbase = (w & 1) * 32;

  for (int k0 = 0; k0 < D_DIM; k0 += 32) {
    __builtin_amdgcn_global_load_lds((const GLOBAL_AS unsigned int*)(gA0 + k0), (LDS_AS unsigned int*)lA0, 16, 0, 0);
    __builtin_amdgcn_global_load_lds((const GLOBAL_AS unsigned int*)(gA1 + k0), (LDS_AS unsigned int*)lA1, 16, 0, 0);
    __builtin_amdgcn_global_load_lds((const GLOBAL_AS unsigned int*)(gB0 + k0), (LDS_AS unsigned int*)lB0, 16, 0, 0);
    __syncthreads();
    bf16x8 af[4], bfr[2];
#pragma unroll
    for (int i = 0; i < 4; ++i)
      af[i] = *(const bf16x8*)&sA[(mbase + i * 16 + lm) * 32 + lq * 8];
#pragma unroll
    for (int j = 0; j < 2; ++j)
      bfr[j] = *(const bf16x8*)&sB[(nbase + j * 16 + lm) * 32 + lq * 8];
#pragma unroll
    for (int i = 0; i < 4; ++i)
#pragma unroll
      for (int j = 0; j < 2; ++j)
        acc[i][j] = __builtin_amdgcn_mfma_f32_16x16x32_bf16(af[i], bfr[j], acc[i][j], 0, 0, 0);
    __syncthreads();
  }
#pragma unroll
  for (int i = 0; i < 4; ++i) {
    const int rb = rowA0 + mbase + i * 16 + lq * 4;
#pragma unroll
    for (int j = 0; j < 2; ++j) {
      const int q = rowB0 + nbase + j * 16 + lm;
      const float bias = bdde[q];
#pragma unroll
      for (int r = 0; r < 4; ++r) {
        const int row = rb + r;
        float z = acc[i][j][r] + bias;
        float gate = 1.0f / (1.0f + expf(-z));
        size_t qi = (size_t)row * Q_DIM + q;
        float4 sq = ((const float4*)state)[qi];
        float4 nq = ((const float4*)out)[qi];   // ns f32 written by k_gemm1
        float4 f;
        f.x = sq.x + gate * (nq.x - sq.x);
        f.y = sq.y + gate * (nq.y - sq.y);
        f.z = sq.z + gate * (nq.z - sq.z);
        f.w = sq.w + gate * (nq.w - sq.w);
        ((float4*)out)[qi] = f;                 // in-place: same thread read->write
      }
    }
  }
}

// ---------------- K3: eta ----------------
__global__ void k_eta(const float* __restrict__ drift, float* __restrict__ out_eta) {
  *out_eta = *drift * (1.0f / 2097152.0f);  // mean over B*Q
}

extern "C" void kernel_launch(void* const* d_in, const int* in_sizes, int n_in,
                              void* d_out, int out_size, void* d_ws, size_t ws_size,
                              hipStream_t stream) {
  // Inputs f32 (round-2 NaN proves bf16 misread explodes); output f32 buffer,
  // compared in bf16-cast space by the harness.
  const float* x     = (const float*)d_in[0];
  const float* state = (const float*)d_in[1];
  const float* wphi  = (const float*)d_in[2];
  const float* bphi  = (const float*)d_in[3];
  const float* wdde  = (const float*)d_in[4];
  const float* bdde  = (const float*)d_in[5];
  float* out = (float*)d_out;
  char* ws = (char*)d_ws;
  // ws layout (bytes): [0,16M) x_bf16 | [16M,48M) Wphi_bf16 | [48M,56M) Wdde_bf16
  //                    [56M,72M) ns_bf16 | [72M,+4) drift accumulator
  unsigned short* xb    = (unsigned short*)(ws);
  unsigned short* wphib = (unsigned short*)(ws + 16777216);
  unsigned short* wddeb = (unsigned short*)(ws + 50331648);
  unsigned short* nsb   = (unsigned short*)(ws + 58720256);
  float* drift          = (float*)(ws + 75497472);

  k_convert<<<28672, 256, 0, stream>>>(x, wphi, wdde, xb, wphib, wddeb, drift);
  dim3 g1(32, 16);
  k_gemm1<<<g1, 256, 0, stream>>>(xb, wphib, bphi, state, out, nsb, drift);
  dim3 g2(16, 16);
  k_gemm2<<<g2, 256, 0, stream>>>(nsb, wddeb, bdde, state, out);
  k_eta<<<1, 1, 0, stream>>>(drift, out + (out_size - 1));
}

// Round 4
// 374.978 us; speedup vs baseline: 3.3610x; 3.3610x over previous
//
#include <hip/hip_runtime.h>
#include <stdint.h>

#define GLOBAL_AS __attribute__((address_space(1)))
#define LDS_AS    __attribute__((address_space(3)))

typedef __attribute__((ext_vector_type(8))) short bf16x8;   // 8 bf16 = 4 VGPRs
typedef __attribute__((ext_vector_type(4))) float f32x4;

#define B_DIM 2048
#define D_DIM 4096
#define Q_DIM 1024
#define EPSF  1e-8f

__device__ __forceinline__ unsigned short f2bf(float f) {
  union { float f; unsigned int u; } v; v.f = f;
  unsigned int u = v.u;
  u += 0x7FFFu + ((u >> 16) & 1u);   // round-to-nearest-even
  return (unsigned short)(u >> 16);
}

// ---------------- K0: f32 -> bf16 conversion (x, W_phi, W_dde) ----------------
#define NX4    2097152u   // 2048*4096/4
#define NWPHI4 4194304u   // 4096*4096/4
#define NWDDE4 1048576u   // 1024*4096/4

__global__ __launch_bounds__(256) void k_convert(
    const float* __restrict__ x, const float* __restrict__ wphi,
    const float* __restrict__ wdde,
    unsigned short* __restrict__ xb, unsigned short* __restrict__ wphib,
    unsigned short* __restrict__ wddeb, float* __restrict__ drift) {
  unsigned int idx = blockIdx.x * 256u + threadIdx.x;
  if (idx == 0) *drift = 0.0f;
  const float4* s; ushort4* d; unsigned int local;
  if (idx < NX4)              { s = (const float4*)x;    d = (ushort4*)xb;    local = idx; }
  else if (idx < NX4 + NWPHI4){ s = (const float4*)wphi; d = (ushort4*)wphib; local = idx - NX4; }
  else                        { s = (const float4*)wdde; d = (ushort4*)wddeb; local = idx - (NX4 + NWPHI4); }
  float4 v = s[local];
  d[local] = make_ushort4(f2bf(v.x), f2bf(v.y), f2bf(v.z), f2bf(v.w));
}

// ---------------- K1: GEMM1 (v = x * W_phi^T) + quaternion epilogue ----------------
// A = x bf16 [2048,4096], B = W_phi bf16 [4096,4096] (both K-contiguous).
// 128x128 tile, BK=32, 256 threads = 4 waves in 2x2, each wave 64x64 (4x4 MFMA tiles).
// Epilogue: per-wave LDS transpose; i-loop MUST be fully unrolled — runtime
// indexing of acc[i] forces the accumulator into scratch (R3: 3.47 GB HBM
// writes, 1047 us). All acc indices compile-time => acc stays in AGPRs.
__global__ __launch_bounds__(256) void k_gemm1(
    const unsigned short* __restrict__ A, const unsigned short* __restrict__ Bm,
    const float* __restrict__ bphi, const float* __restrict__ state,
    float* __restrict__ nsf /* d_out as [2048,4096] f32 next_state */,
    unsigned short* __restrict__ nsb /* ws: next_state bf16 */,
    float* __restrict__ drift) {
  __shared__ __align__(16) unsigned short sAB[2 * 128 * 32];  // sA=[0,4096), sB=[4096,8192)
  const int t = threadIdx.x;
  const int lane = t & 63;
  const int w = t >> 6;
  const int bn = blockIdx.x;   // 0..31  (cols = W_phi rows)
  const int bm = blockIdx.y;   // 0..15  (x rows)
  const int rowA0 = bm * 128;
  const int rowB0 = bn * 128;

  // staging: chunk c covers 16B; row = c>>2, k-offset = (c&3)*8 elements
  const int c0 = t, c1 = t + 256;
  const unsigned short* gA0 = A  + (size_t)(rowA0 + (c0 >> 2)) * D_DIM + (c0 & 3) * 8;
  const unsigned short* gA1 = A  + (size_t)(rowA0 + (c1 >> 2)) * D_DIM + (c1 & 3) * 8;
  const unsigned short* gB0 = Bm + (size_t)(rowB0 + (c0 >> 2)) * D_DIM + (c0 & 3) * 8;
  const unsigned short* gB1 = Bm + (size_t)(rowB0 + (c1 >> 2)) * D_DIM + (c1 & 3) * 8;
  unsigned short* lA0 = &sAB[c0 * 8];
  unsigned short* lA1 = &sAB[c1 * 8];
  unsigned short* lB0 = &sAB[4096 + c0 * 8];
  unsigned short* lB1 = &sAB[4096 + c1 * 8];

  f32x4 acc[4][4] = {};
  const int lm = lane & 15;
  const int lq = lane >> 4;
  const int mbase = (w >> 1) * 64;
  const int nbase = (w & 1) * 64;

  for (int k0 = 0; k0 < D_DIM; k0 += 32) {
    __builtin_amdgcn_global_load_lds((const GLOBAL_AS unsigned int*)(gA0 + k0), (LDS_AS unsigned int*)lA0, 16, 0, 0);
    __builtin_amdgcn_global_load_lds((const GLOBAL_AS unsigned int*)(gA1 + k0), (LDS_AS unsigned int*)lA1, 16, 0, 0);
    __builtin_amdgcn_global_load_lds((const GLOBAL_AS unsigned int*)(gB0 + k0), (LDS_AS unsigned int*)lB0, 16, 0, 0);
    __builtin_amdgcn_global_load_lds((const GLOBAL_AS unsigned int*)(gB1 + k0), (LDS_AS unsigned int*)lB1, 16, 0, 0);
    __syncthreads();
    bf16x8 af[4], bfr[4];
#pragma unroll
    for (int i = 0; i < 4; ++i)
      af[i] = *(const bf16x8*)&sAB[(mbase + i * 16 + lm) * 32 + lq * 8];
#pragma unroll
    for (int j = 0; j < 4; ++j)
      bfr[j] = *(const bf16x8*)&sAB[4096 + (nbase + j * 16 + lm) * 32 + lq * 8];
#pragma unroll
    for (int i = 0; i < 4; ++i)
#pragma unroll
      for (int j = 0; j < 4; ++j)
        acc[i][j] = __builtin_amdgcn_mfma_f32_16x16x32_bf16(af[i], bfr[j], acc[i][j], 0, 0, 0);
    __syncthreads();
  }

  // ---- epilogue: per-wave 16x64 f32 scratch in the (now free) staging LDS ----
  // C/D layout: col = lane&15, row = (lane>>4)*4 + reg  [m89-verified]
  float* cscr = ((float*)sAB) + w * 1024;       // 4 KB per wave, 16 KB total
  float driftLocal = 0.0f;
  const int colBase = rowB0 + nbase;            // wave's global col 0 (multiple of 64)
  const int qBase = colBase >> 2;               // global quaternion base
#pragma unroll
  for (int i = 0; i < 4; ++i) {                 // FULLY UNROLLED (see header comment)
    __syncthreads();                            // previous iter's reads done (all waves)
#pragma unroll
    for (int j = 0; j < 4; ++j)
#pragma unroll
      for (int r = 0; r < 4; ++r)
        cscr[(lq * 4 + r) * 64 + j * 16 + lm] = acc[i][j][r];
    __syncthreads();                            // writes visible
#pragma unroll
    for (int s = 0; s < 4; ++s) {
      const int qlin = s * 64 + lane;           // 0..255 over 16 rows x 16 quats
      const int lrow = qlin >> 4;               // 0..15
      const int qc = qlin & 15;                 // 0..15
      float4 vq = *(const float4*)&cscr[lrow * 64 + qc * 4];
      float4 bq = ((const float4*)bphi)[qBase + qc];
      float vx = vq.y + bq.y, vy = vq.z + bq.z, vz = vq.w + bq.w;  // v[...,1:]
      // exp_map (reference: theta includes +EPS; axis = v/theta)
      float th = sqrtf(vx * vx + vy * vy + vz * vz) + EPSF;
      float st = sinf(th), ct = cosf(th);
      float sc = st / th;
      float rw = ct, rx = vx * sc, ry = vy * sc, rz = vz * sc;
      const int grow = rowA0 + mbase + i * 16 + lrow;
      const size_t qgi = (size_t)grow * Q_DIM + (qBase + qc);
      float4 sq = ((const float4*)state)[qgi];
      float aw = sq.x, ax = sq.y, ay = sq.z, az = sq.w;
      // qmul(state, rotation)
      float nw = aw * rw - ax * rx - ay * ry - az * rz;
      float nx = aw * rx + rw * ax + (ay * rz - az * ry);
      float ny = aw * ry + rw * ay + (az * rx - ax * rz);
      float nz = aw * rz + rw * az + (ax * ry - ay * rx);
      // qnormalize
      float nrm = sqrtf(nw * nw + nx * nx + ny * ny + nz * nz);
      float invn = 1.0f / (nrm + EPSF);
      nw *= invn; nx *= invn; ny *= invn; nz *= invn;
      float n2 = sqrtf(nw * nw + nx * nx + ny * ny + nz * nz);
      driftLocal += fabsf(n2 - 1.0f);
      float4 o; o.x = nw; o.y = nx; o.z = ny; o.w = nz;
      ((float4*)nsf)[qgi] = o;                  // f32 next_state (blend source)
      ((ushort4*)nsb)[qgi] = make_ushort4(f2bf(nw), f2bf(nx), f2bf(ny), f2bf(nz));
    }
  }
#pragma unroll
  for (int off = 32; off > 0; off >>= 1) driftLocal += __shfl_down(driftLocal, off);
  if (lane == 0) atomicAdd(drift, driftLocal);
}

// ---------------- K2: GEMM2 (logits = ns * W_dde^T) + gate/blend epilogue ----------------
// 128x64 tile -> 16x16 = 256 blocks. 4 waves in 2x2, each wave 64x32 (4x2 MFMA tiles).
__global__ __launch_bounds__(256) void k_gemm2(
    const unsigned short* __restrict__ A /* ns bf16 [2048,4096] */,
    const unsigned short* __restrict__ Bm /* W_dde bf16 [1024,4096] */,
    const float* __restrict__ bdde, const float* __restrict__ state,
    float* __restrict__ out /* d_out f32: holds ns, overwritten in place */) {
  __shared__ unsigned short sA[128 * 32];  // 8 KB
  __shared__ unsigned short sB[64 * 32];   // 4 KB
  const int t = threadIdx.x;
  const int lane = t & 63;
  const int w = t >> 6;
  const int bn = blockIdx.x;  // 0..15 (q tiles)
  const int bm = blockIdx.y;  // 0..15 (rows)
  const int rowA0 = bm * 128;
  const int rowB0 = bn * 64;
  const int c0 = t, c1 = t + 256;
  const unsigned short* gA0 = A  + (size_t)(rowA0 + (c0 >> 2)) * D_DIM + (c0 & 3) * 8;
  const unsigned short* gA1 = A  + (size_t)(rowA0 + (c1 >> 2)) * D_DIM + (c1 & 3) * 8;
  const unsigned short* gB0 = Bm + (size_t)(rowB0 + (c0 >> 2)) * D_DIM + (c0 & 3) * 8;
  unsigned short* lA0 = &sA[c0 * 8];
  unsigned short* lA1 = &sA[c1 * 8];
  unsigned short* lB0 = &sB[c0 * 8];

  f32x4 acc[4][2] = {};
  const int lm = lane & 15, lq = lane >> 4;
  const int mbase = (w >> 1) * 64, nbase = (w & 1) * 32;

  for (int k0 = 0; k0 < D_DIM; k0 += 32) {
    __builtin_amdgcn_global_load_lds((const GLOBAL_AS unsigned int*)(gA0 + k0), (LDS_AS unsigned int*)lA0, 16, 0, 0);
    __builtin_amdgcn_global_load_lds((const GLOBAL_AS unsigned int*)(gA1 + k0), (LDS_AS unsigned int*)lA1, 16, 0, 0);
    __builtin_amdgcn_global_load_lds((const GLOBAL_AS unsigned int*)(gB0 + k0), (LDS_AS unsigned int*)lB0, 16, 0, 0);
    __syncthreads();
    bf16x8 af[4], bfr[2];
#pragma unroll
    for (int i = 0; i < 4; ++i)
      af[i] = *(const bf16x8*)&sA[(mbase + i * 16 + lm) * 32 + lq * 8];
#pragma unroll
    for (int j = 0; j < 2; ++j)
      bfr[j] = *(const bf16x8*)&sB[(nbase + j * 16 + lm) * 32 + lq * 8];
#pragma unroll
    for (int i = 0; i < 4; ++i)
#pragma unroll
      for (int j = 0; j < 2; ++j)
        acc[i][j] = __builtin_amdgcn_mfma_f32_16x16x32_bf16(af[i], bfr[j], acc[i][j], 0, 0, 0);
    __syncthreads();
  }
#pragma unroll
  for (int i = 0; i < 4; ++i) {
    const int rb = rowA0 + mbase + i * 16 + lq * 4;
#pragma unroll
    for (int j = 0; j < 2; ++j) {
      const int q = rowB0 + nbase + j * 16 + lm;
      const float bias = bdde[q];
#pragma unroll
      for (int r = 0; r < 4; ++r) {
        const int row = rb + r;
        float z = acc[i][j][r] + bias;
        float gate = 1.0f / (1.0f + expf(-z));
        size_t qi = (size_t)row * Q_DIM + q;
        float4 sq = ((const float4*)state)[qi];
        float4 nq = ((const float4*)out)[qi];   // ns f32 written by k_gemm1
        float4 f;
        f.x = sq.x + gate * (nq.x - sq.x);
        f.y = sq.y + gate * (nq.y - sq.y);
        f.z = sq.z + gate * (nq.z - sq.z);
        f.w = sq.w + gate * (nq.w - sq.w);
        ((float4*)out)[qi] = f;                 // in-place: same thread read->write
      }
    }
  }
}

// ---------------- K3: eta ----------------
__global__ void k_eta(const float* __restrict__ drift, float* __restrict__ out_eta) {
  *out_eta = *drift * (1.0f / 2097152.0f);  // mean over B*Q
}

extern "C" void kernel_launch(void* const* d_in, const int* in_sizes, int n_in,
                              void* d_out, int out_size, void* d_ws, size_t ws_size,
                              hipStream_t stream) {
  const float* x     = (const float*)d_in[0];
  const float* state = (const float*)d_in[1];
  const float* wphi  = (const float*)d_in[2];
  const float* bphi  = (const float*)d_in[3];
  const float* wdde  = (const float*)d_in[4];
  const float* bdde  = (const float*)d_in[5];
  float* out = (float*)d_out;
  char* ws = (char*)d_ws;
  // ws layout (bytes): [0,16M) x_bf16 | [16M,48M) Wphi_bf16 | [48M,56M) Wdde_bf16
  //                    [56M,72M) ns_bf16 | [72M,+4) drift accumulator
  unsigned short* xb    = (unsigned short*)(ws);
  unsigned short* wphib = (unsigned short*)(ws + 16777216);
  unsigned short* wddeb = (unsigned short*)(ws + 50331648);
  unsigned short* nsb   = (unsigned short*)(ws + 58720256);
  float* drift          = (float*)(ws + 75497472);

  k_convert<<<28672, 256, 0, stream>>>(x, wphi, wdde, xb, wphib, wddeb, drift);
  dim3 g1(32, 16);
  k_gemm1<<<g1, 256, 0, stream>>>(xb, wphib, bphi, state, out, nsb, drift);
  dim3 g2(16, 16);
  k_gemm2<<<g2, 256, 0, stream>>>(nsb, wddeb, bdde, state, out);
  k_eta<<<1, 1, 0, stream>>>(drift, out + (out_size - 1));
}

// Round 5
// 330.976 us; speedup vs baseline: 3.8079x; 1.1329x over previous
//
#include <hip/hip_runtime.h>
#include <stdint.h>

#define GLOBAL_AS __attribute__((address_space(1)))
#define LDS_AS    __attribute__((address_space(3)))

typedef __attribute__((ext_vector_type(8))) short bf16x8;   // 8 bf16 = 4 VGPRs
typedef __attribute__((ext_vector_type(4))) float f32x4;

#define B_DIM 2048
#define D_DIM 4096
#define Q_DIM 1024
#define EPSF  1e-8f

__device__ __forceinline__ unsigned short f2bf(float f) {
  union { float f; unsigned int u; } v; v.f = f;
  unsigned int u = v.u;
  u += 0x7FFFu + ((u >> 16) & 1u);   // round-to-nearest-even
  return (unsigned short)(u >> 16);
}

// ---------------- K0: f32 -> bf16 conversion (x, W_phi, W_dde) ----------------
#define NX4    2097152u   // 2048*4096/4
#define NWPHI4 4194304u   // 4096*4096/4
#define NWDDE4 1048576u   // 1024*4096/4

__global__ __launch_bounds__(256) void k_convert(
    const float* __restrict__ x, const float* __restrict__ wphi,
    const float* __restrict__ wdde,
    unsigned short* __restrict__ xb, unsigned short* __restrict__ wphib,
    unsigned short* __restrict__ wddeb, float* __restrict__ drift) {
  unsigned int idx = blockIdx.x * 256u + threadIdx.x;
  if (idx == 0) *drift = 0.0f;
  const float4* s; ushort4* d; unsigned int local;
  if (idx < NX4)              { s = (const float4*)x;    d = (ushort4*)xb;    local = idx; }
  else if (idx < NX4 + NWPHI4){ s = (const float4*)wphi; d = (ushort4*)wphib; local = idx - NX4; }
  else                        { s = (const float4*)wdde; d = (ushort4*)wddeb; local = idx - (NX4 + NWPHI4); }
  float4 v = s[local];
  d[local] = make_ushort4(f2bf(v.x), f2bf(v.y), f2bf(v.z), f2bf(v.w));
}

// Swizzle: LDS chunk c (16B) holds global k-chunk (c&7)^((c>>3)&7) of row c>>3.
// Fragment read of k-chunk kc, row r -> LDS chunk r*8 + (kc ^ (r&7)).
// Bank math: row stride 64 el = 32 dwords -> addr mod 32 = (kc^(lm&7))*4 -> 8
// distinct bank-quads over 16 lanes -> 2-way aliasing = free (m136).

// ---------------- K1: GEMM1 (v = x * W_phi^T) + quaternion epilogue ----------------
// 128x128 tile, BK=64, swizzled LDS; 4 waves 2x2, each 64x64 (4x4 MFMA tiles).
// acc indices must stay compile-time (R3: runtime index => scratch spill, 6.7x).
__global__ __launch_bounds__(256) void k_gemm1(
    const unsigned short* __restrict__ A, const unsigned short* __restrict__ Bm,
    const float* __restrict__ bphi, const float* __restrict__ state,
    float* __restrict__ nsf /* d_out as [2048,4096] f32 next_state */,
    unsigned short* __restrict__ nsb /* ws: next_state bf16 */,
    float* __restrict__ drift) {
  __shared__ __align__(16) unsigned short sAB[2 * 128 * 64];  // 32 KB: sA [0,8192), sB [8192,16384)
  const int t = threadIdx.x;
  const int lane = t & 63;
  const int w = t >> 6;
  const int bn = blockIdx.x;   // 0..31
  const int bm = blockIdx.y;   // 0..15
  const int rowA0 = bm * 128;
  const int rowB0 = bn * 128;

  // staging: 1024 chunks per matrix, 4 passes of 256 threads
  const unsigned short* gA[4]; const unsigned short* gB[4];
  unsigned short *lA[4], *lB[4];
#pragma unroll
  for (int p = 0; p < 4; ++p) {
    const int c = t + p * 256;
    const int row = c >> 3;
    const int kcg = (c & 7) ^ (row & 7);           // swizzled global k-chunk
    gA[p] = A  + (size_t)(rowA0 + row) * D_DIM + kcg * 8;
    gB[p] = Bm + (size_t)(rowB0 + row) * D_DIM + kcg * 8;
    lA[p] = &sAB[c * 8];
    lB[p] = &sAB[8192 + c * 8];
  }

  f32x4 acc[4][4] = {};
  const int lm = lane & 15;
  const int lq = lane >> 4;
  const int mbase = (w >> 1) * 64;
  const int nbase = (w & 1) * 64;
  const int rsw = lm & 7;                          // (row&7) for all fragment rows

  for (int k0 = 0; k0 < D_DIM; k0 += 64) {
#pragma unroll
    for (int p = 0; p < 4; ++p) {
      __builtin_amdgcn_global_load_lds((const GLOBAL_AS unsigned int*)(gA[p] + k0), (LDS_AS unsigned int*)lA[p], 16, 0, 0);
      __builtin_amdgcn_global_load_lds((const GLOBAL_AS unsigned int*)(gB[p] + k0), (LDS_AS unsigned int*)lB[p], 16, 0, 0);
    }
    __syncthreads();
#pragma unroll
    for (int ks = 0; ks < 2; ++ks) {
      const int kc = ks * 4 + lq;                  // k-chunk 0..7
      const int csw = (kc ^ rsw) * 8;              // swizzled element offset in row
      bf16x8 af[4], bfr[4];
#pragma unroll
      for (int i = 0; i < 4; ++i)
        af[i] = *(const bf16x8*)&sAB[(mbase + i * 16 + lm) * 64 + csw];
#pragma unroll
      for (int j = 0; j < 4; ++j)
        bfr[j] = *(const bf16x8*)&sAB[8192 + (nbase + j * 16 + lm) * 64 + csw];
#pragma unroll
      for (int i = 0; i < 4; ++i)
#pragma unroll
        for (int j = 0; j < 4; ++j)
          acc[i][j] = __builtin_amdgcn_mfma_f32_16x16x32_bf16(af[i], bfr[j], acc[i][j], 0, 0, 0);
    }
    __syncthreads();
  }

  // ---- epilogue (verbatim from passing R4): per-wave 16x64 f32 LDS transpose ----
  // C/D layout: col = lane&15, row = (lane>>4)*4 + reg  [m89-verified]
  float* cscr = ((float*)sAB) + w * 1024;       // 4 KB per wave, 16 KB of 32 KB
  float driftLocal = 0.0f;
  const int colBase = rowB0 + nbase;
  const int qBase = colBase >> 2;
#pragma unroll
  for (int i = 0; i < 4; ++i) {                 // FULLY UNROLLED (acc in AGPRs)
    __syncthreads();
#pragma unroll
    for (int j = 0; j < 4; ++j)
#pragma unroll
      for (int r = 0; r < 4; ++r)
        cscr[(lq * 4 + r) * 64 + j * 16 + lm] = acc[i][j][r];
    __syncthreads();
#pragma unroll
    for (int s = 0; s < 4; ++s) {
      const int qlin = s * 64 + lane;
      const int lrow = qlin >> 4;
      const int qc = qlin & 15;
      float4 vq = *(const float4*)&cscr[lrow * 64 + qc * 4];
      float4 bq = ((const float4*)bphi)[qBase + qc];
      float vx = vq.y + bq.y, vy = vq.z + bq.z, vz = vq.w + bq.w;
      float th = sqrtf(vx * vx + vy * vy + vz * vz) + EPSF;
      float st = sinf(th), ct = cosf(th);
      float sc = st / th;
      float rw = ct, rx = vx * sc, ry = vy * sc, rz = vz * sc;
      const int grow = rowA0 + mbase + i * 16 + lrow;
      const size_t qgi = (size_t)grow * Q_DIM + (qBase + qc);
      float4 sq = ((const float4*)state)[qgi];
      float aw = sq.x, ax = sq.y, ay = sq.z, az = sq.w;
      float nw = aw * rw - ax * rx - ay * ry - az * rz;
      float nx = aw * rx + rw * ax + (ay * rz - az * ry);
      float ny = aw * ry + rw * ay + (az * rx - ax * rz);
      float nz = aw * rz + rw * az + (ax * ry - ay * rx);
      float nrm = sqrtf(nw * nw + nx * nx + ny * ny + nz * nz);
      float invn = 1.0f / (nrm + EPSF);
      nw *= invn; nx *= invn; ny *= invn; nz *= invn;
      float n2 = sqrtf(nw * nw + nx * nx + ny * ny + nz * nz);
      driftLocal += fabsf(n2 - 1.0f);
      float4 o; o.x = nw; o.y = nx; o.z = ny; o.w = nz;
      ((float4*)nsf)[qgi] = o;
      ((ushort4*)nsb)[qgi] = make_ushort4(f2bf(nw), f2bf(nx), f2bf(ny), f2bf(nz));
    }
  }
#pragma unroll
  for (int off = 32; off > 0; off >>= 1) driftLocal += __shfl_down(driftLocal, off);
  if (lane == 0) atomicAdd(drift, driftLocal);
}

// ---------------- K2: GEMM2 (logits = ns * W_dde^T) + gate/blend epilogue ----------------
// 64x64 tile, BK=64, swizzled -> grid (16,32) = 512 blocks (2/CU, was 1/CU).
// 4 waves 2x2, each wave 32x32 (2x2 MFMA tiles).
__global__ __launch_bounds__(256) void k_gemm2(
    const unsigned short* __restrict__ A /* ns bf16 [2048,4096] */,
    const unsigned short* __restrict__ Bm /* W_dde bf16 [1024,4096] */,
    const float* __restrict__ bdde, const float* __restrict__ state,
    float* __restrict__ out /* d_out f32: holds ns, overwritten in place */) {
  __shared__ __align__(16) unsigned short sAB[2 * 64 * 64];  // 16 KB
  const int t = threadIdx.x;
  const int lane = t & 63;
  const int w = t >> 6;
  const int bn = blockIdx.x;  // 0..15 (q tiles)
  const int bm = blockIdx.y;  // 0..31 (row tiles)
  const int rowA0 = bm * 64;
  const int rowB0 = bn * 64;

  const unsigned short* gA[2]; const unsigned short* gB[2];
  unsigned short *lA[2], *lB[2];
#pragma unroll
  for (int p = 0; p < 2; ++p) {
    const int c = t + p * 256;                     // 512 chunks per matrix
    const int row = c >> 3;
    const int kcg = (c & 7) ^ (row & 7);
    gA[p] = A  + (size_t)(rowA0 + row) * D_DIM + kcg * 8;
    gB[p] = Bm + (size_t)(rowB0 + row) * D_DIM + kcg * 8;
    lA[p] = &sAB[c * 8];
    lB[p] = &sAB[4096 + c * 8];
  }

  f32x4 acc[2][2] = {};
  const int lm = lane & 15, lq = lane >> 4;
  const int mbase = (w >> 1) * 32, nbase = (w & 1) * 32;
  const int rsw = lm & 7;

  for (int k0 = 0; k0 < D_DIM; k0 += 64) {
#pragma unroll
    for (int p = 0; p < 2; ++p) {
      __builtin_amdgcn_global_load_lds((const GLOBAL_AS unsigned int*)(gA[p] + k0), (LDS_AS unsigned int*)lA[p], 16, 0, 0);
      __builtin_amdgcn_global_load_lds((const GLOBAL_AS unsigned int*)(gB[p] + k0), (LDS_AS unsigned int*)lB[p], 16, 0, 0);
    }
    __syncthreads();
#pragma unroll
    for (int ks = 0; ks < 2; ++ks) {
      const int kc = ks * 4 + lq;
      const int csw = (kc ^ rsw) * 8;
      bf16x8 af[2], bfr[2];
#pragma unroll
      for (int i = 0; i < 2; ++i)
        af[i] = *(const bf16x8*)&sAB[(mbase + i * 16 + lm) * 64 + csw];
#pragma unroll
      for (int j = 0; j < 2; ++j)
        bfr[j] = *(const bf16x8*)&sAB[4096 + (nbase + j * 16 + lm) * 64 + csw];
#pragma unroll
      for (int i = 0; i < 2; ++i)
#pragma unroll
        for (int j = 0; j < 2; ++j)
          acc[i][j] = __builtin_amdgcn_mfma_f32_16x16x32_bf16(af[i], bfr[j], acc[i][j], 0, 0, 0);
    }
    __syncthreads();
  }
#pragma unroll
  for (int i = 0; i < 2; ++i) {
    const int rb = rowA0 + mbase + i * 16 + lq * 4;
#pragma unroll
    for (int j = 0; j < 2; ++j) {
      const int q = rowB0 + nbase + j * 16 + lm;
      const float bias = bdde[q];
#pragma unroll
      for (int r = 0; r < 4; ++r) {
        const int row = rb + r;
        float z = acc[i][j][r] + bias;
        float gate = 1.0f / (1.0f + expf(-z));
        size_t qi = (size_t)row * Q_DIM + q;
        float4 sq = ((const float4*)state)[qi];
        float4 nq = ((const float4*)out)[qi];   // ns f32 written by k_gemm1
        float4 f;
        f.x = sq.x + gate * (nq.x - sq.x);
        f.y = sq.y + gate * (nq.y - sq.y);
        f.z = sq.z + gate * (nq.z - sq.z);
        f.w = sq.w + gate * (nq.w - sq.w);
        ((float4*)out)[qi] = f;                 // in-place: same thread read->write
      }
    }
  }
}

// ---------------- K3: eta ----------------
__global__ void k_eta(const float* __restrict__ drift, float* __restrict__ out_eta) {
  *out_eta = *drift * (1.0f / 2097152.0f);  // mean over B*Q
}

extern "C" void kernel_launch(void* const* d_in, const int* in_sizes, int n_in,
                              void* d_out, int out_size, void* d_ws, size_t ws_size,
                              hipStream_t stream) {
  const float* x     = (const float*)d_in[0];
  const float* state = (const float*)d_in[1];
  const float* wphi  = (const float*)d_in[2];
  const float* bphi  = (const float*)d_in[3];
  const float* wdde  = (const float*)d_in[4];
  const float* bdde  = (const float*)d_in[5];
  float* out = (float*)d_out;
  char* ws = (char*)d_ws;
  // ws layout (bytes): [0,16M) x_bf16 | [16M,48M) Wphi_bf16 | [48M,56M) Wdde_bf16
  //                    [56M,72M) ns_bf16 | [72M,+4) drift accumulator
  unsigned short* xb    = (unsigned short*)(ws);
  unsigned short* wphib = (unsigned short*)(ws + 16777216);
  unsigned short* wddeb = (unsigned short*)(ws + 50331648);
  unsigned short* nsb   = (unsigned short*)(ws + 58720256);
  float* drift          = (float*)(ws + 75497472);

  k_convert<<<28672, 256, 0, stream>>>(x, wphi, wdde, xb, wphib, wddeb, drift);
  dim3 g1(32, 16);
  k_gemm1<<<g1, 256, 0, stream>>>(xb, wphib, bphi, state, out, nsb, drift);
  dim3 g2(16, 32);
  k_gemm2<<<g2, 256, 0, stream>>>(nsb, wddeb, bdde, state, out);
  k_eta<<<1, 1, 0, stream>>>(drift, out + (out_size - 1));
}